// Round 2
// baseline (249.586 us; speedup 1.0000x reference)
//
#include <hip/hip_runtime.h>
#include <hip/hip_bf16.h>

// Problem constants (match reference)
#define B_  32
#define C_  3
#define HW_ 1024          // N = H*W
#define L_  8             // alphabet
#define P_  16
#define M_  1024
#define NRUN_S  (B_*C_)           // 96
#define NRUN_P  (C_*P_)           // 48
#define NRUN_SP (B_*C_*P_)        // 1536
// Tight dictionary bound for len-2048 LZW over alphabet 8:
// entries are distinct strings of len>=2; 64 len-2 (64 syms) + 512 len-3
// (1024 syms) + 320 len-4 (960 syms) = 896 entries max; nfree <= 8+896 = 904.
#define TRIE_N  904

// ---------------------------------------------------------------------------
// Kernel 1: quantize  strings[b,c,n] = argmin_l |x[b,c,curve[n]] - levels[c,l]|
// ---------------------------------------------------------------------------
__global__ void quantize_kernel(const float* __restrict__ x,
                                const int* __restrict__ curve,
                                const float* __restrict__ levels,
                                unsigned char* __restrict__ strings) {
    int idx = blockIdx.x * blockDim.x + threadIdx.x;   // [0, 96*1024)
    if (idx >= NRUN_S * HW_) return;
    int n  = idx & (HW_ - 1);
    int bc = idx >> 10;            // b*3 + c
    int c  = bc % C_;
    int pix = curve[n];
    float v = x[bc * HW_ + pix];
    float best = fabsf(v - levels[c * L_ + 0]);
    int bi = 0;
#pragma unroll
    for (int l = 1; l < L_; ++l) {
        float d = fabsf(v - levels[c * L_ + l]);
        if (d < best) { best = d; bi = l; }   // strict < : first-min (matches jnp.argmin)
    }
    strings[idx] = (unsigned char)bi;
}

// ---------------------------------------------------------------------------
// Kernel 2: LZW count per run. One block (64 threads) per run; trie in LDS;
// lane 0 walks the serial chain.
//   run < 96          : string run (len 1024)      -> cs[run]
//   96 <= run < 144   : pmap run  (len 1024)       -> cp[run-96]
//   144 <= run < 1680 : concat run (len 2048)      -> csp[run-144]
// ---------------------------------------------------------------------------
__global__ void __launch_bounds__(64)
lzw_kernel(const unsigned char* __restrict__ strings,
           const int* __restrict__ pmaps,
           int* __restrict__ cs, int* __restrict__ cp, int* __restrict__ csp) {
    __shared__ short trie[TRIE_N * L_];
    __shared__ unsigned char seq[2 * HW_];

    const int run = blockIdx.x;
    const int tid = threadIdx.x;

    // parallel trie init to -1 (as 32-bit stores)
    int* trie32 = (int*)trie;
    for (int i = tid; i < TRIE_N * L_ / 2; i += 64) trie32[i] = -1;

    int len = 0, s_len = 0;
    const unsigned char* sp = nullptr;
    const int* pp = nullptr;

    if (run < NRUN_S) {
        sp = strings + run * HW_;  s_len = HW_;  len = HW_;
    } else if (run < NRUN_S + NRUN_P) {
        int idx = run - NRUN_S;                 // c*16 + p
        pp = pmaps + idx * M_;  len = M_;
    } else {
        int idx = run - (NRUN_S + NRUN_P);      // (b*3+c)*16 + p
        int bc = idx >> 4;
        int c  = bc % C_;
        int p  = idx & 15;
        sp = strings + bc * HW_;       s_len = HW_;
        pp = pmaps + (c * P_ + p) * M_;
        len = HW_ + M_;
    }

    if (sp) {  // stage 1024 string bytes (4B at a time)
        const int* s32 = (const int*)sp;
        int* d32 = (int*)seq;
        for (int i = tid; i < HW_ / 4; i += 64) d32[i] = s32[i];
    }
    if (pp) {  // stage 1024 pmap symbols (int32 -> byte)
        for (int i = tid; i < M_; i += 64) seq[s_len + i] = (unsigned char)pp[i];
    }
    __syncthreads();

    if (tid == 0) {
        int cur   = seq[0];
        int nfree = L_;
        int cnt   = 0;
        for (int t = 1; t < len; ++t) {
            int c   = seq[t];
            int a   = cur * L_ + c;
            int nxt = trie[a];                 // sign-extended
            bool hit = (nxt >= 0);
            trie[a] = (short)(hit ? nxt : nfree);   // no-op on hit, register on miss
            cur = hit ? nxt : c;
            if (!hit) { ++nfree; ++cnt; }
        }
        int result = cnt + 1;
        if (run < NRUN_S)                cs[run] = result;
        else if (run < NRUN_S + NRUN_P)  cp[run - NRUN_S] = result;
        else                             csp[run - (NRUN_S + NRUN_P)] = result;
    }
}

// ---------------------------------------------------------------------------
// Kernel 3: NCD epilogue
// out[(b*3+c)*16+p] = (csp - min(cs,cp)) / max(cs,cp)
// ---------------------------------------------------------------------------
__global__ void ncd_kernel(const int* __restrict__ cs,
                           const int* __restrict__ cp,
                           const int* __restrict__ csp,
                           float* __restrict__ out) {
    int idx = blockIdx.x * blockDim.x + threadIdx.x;
    if (idx >= NRUN_SP) return;
    int p  = idx & 15;
    int bc = idx >> 4;         // b*3 + c
    int c  = bc % C_;
    float a  = (float)cs[bc];
    float b  = (float)cp[c * P_ + p];
    float ab = (float)csp[idx];
    out[idx] = (ab - fminf(a, b)) / fmaxf(a, b);
}

// ---------------------------------------------------------------------------
extern "C" void kernel_launch(void* const* d_in, const int* in_sizes, int n_in,
                              void* d_out, int out_size, void* d_ws, size_t ws_size,
                              hipStream_t stream) {
    const float* x      = (const float*)d_in[0];   // [B,C,H,W] f32
    const int*   curve  = (const int*)d_in[1];     // [N] int32
    const float* levels = (const float*)d_in[2];   // [C,L] f32
    const int*   pmaps  = (const int*)d_in[3];     // [C,P,M] int32
    // d_in[4] = i (unused)

    float* out = (float*)d_out;

    unsigned char* strings = (unsigned char*)d_ws;            // 96*1024 bytes
    int* cs  = (int*)((char*)d_ws + NRUN_S * HW_);            // 96
    int* cp  = cs + NRUN_S;                                   // 48
    int* csp = cp + NRUN_P;                                   // 1536

    quantize_kernel<<<(NRUN_S * HW_ + 255) / 256, 256, 0, stream>>>(x, curve, levels, strings);
    lzw_kernel<<<NRUN_S + NRUN_P + NRUN_SP, 64, 0, stream>>>(strings, pmaps, cs, cp, csp);
    ncd_kernel<<<(NRUN_SP + 255) / 256, 256, 0, stream>>>(cs, cp, csp, out);
}